// Round 11
// baseline (1143.061 us; speedup 1.0000x reference)
//
#include <hip/hip_runtime.h>

typedef __bf16 bf16_t;
typedef __attribute__((ext_vector_type(8))) __bf16 bf16x8;
typedef __attribute__((ext_vector_type(4))) float f32x4;
typedef unsigned short u16;
typedef unsigned int u32;
typedef unsigned long long u64;

#define TC 128      // steps per chunk
#define NCHUNK 8
#define XGHALF 16777216  // u16 elements per xg half-buffer (32 MB)
#define LDA 264   // 256 + 8 bf16 pad
#define LOG2E 1.44269504f

// LDS-visibility-only barrier: leaves global prefetch loads (vmcnt) in flight.
#define LDS_BARRIER() asm volatile("s_waitcnt lgkmcnt(0)\n\ts_barrier" ::: "memory")

#if __has_builtin(__builtin_amdgcn_exp2f)
#define EXP2F __builtin_amdgcn_exp2f
#else
static __device__ __forceinline__ float EXP2F(float x) {
  float r;
  asm volatile("v_exp_f32 %0, %1\n\ts_nop 1" : "=v"(r) : "v"(x));
  return r;
}
#endif

// ws layout (bytes), total ~72.5 MB (within the 72.9 MB proven in R1-R10):
//   xg   @ 0         : 2 half-buffers x 64*128*2048*2 = 67,108,864
//   embb @ 67108864  : 10000*256*2 = 5,120,000
//   wkt  @ 72228864  : 512*256*2   =   262,144
//   flags@ 72491008  : 16 ints (xgemm_done[8], scan_done[8]) -- memset 0
//
// xg layout per half (u16): off = ((g*128 + t)*2048) + tile*64 + c16*4 + row4
//   g = b>>2 (scan wg), row4 = b&3, t = chunk-local step, tile = col>>4,
//   c16 = col&15. Scan lane (w,quad,l16) gate j reads (w+8j)*64 + l16*4 + quad.
//
// Pipeline: wgs 0-63 scan chunk c while wgs 64-255 (192 workers) build
// chunk c+1 in the other half. Agent-scope acquire/release flags; workers
// wait scan_done[c-2] before overwriting a half; scan waits xgemm_done[c].

static __device__ __forceinline__ u16 bf16bits(float v) {
  return __builtin_bit_cast(u16, (bf16_t)v);
}
static __device__ __forceinline__ float bf16f(u16 v) {
  return __builtin_bit_cast(float, (u32)v << 16);
}
static __device__ __forceinline__ void spin_ge(int* p, int v) {
  while (__hip_atomic_load(p, __ATOMIC_ACQUIRE, __HIP_MEMORY_SCOPE_AGENT) < v)
    __builtin_amdgcn_s_sleep(8);
}
static __device__ __forceinline__ void sig(int* p) {
  __hip_atomic_fetch_add(p, 1, __ATOMIC_RELEASE, __HIP_MEMORY_SCOPE_AGENT);
}

__global__ __launch_bounds__(256) void k_cvt_emb(const float* __restrict__ e,
                                                 u16* __restrict__ o, int n) {
  int i = blockIdx.x * 256 + threadIdx.x;
  if (i < n) o[i] = bf16bits(e[i]);
}

// WkT[n][k] = Wk[k][n]  (Wk is [256][512] row-major)
__global__ __launch_bounds__(256) void k_wkt(const float* __restrict__ wk,
                                             u16* __restrict__ o) {
  int i = blockIdx.x * 256 + threadIdx.x;  // 131072 total
  int k = i & 255, n = i >> 8;
  o[i] = bf16bits(wk[k * 512 + n]);
}

__global__ __launch_bounds__(512, 2) void k_pipe(
    const int* __restrict__ x, const u16* __restrict__ embb,
    const u16* __restrict__ wkt, const float* __restrict__ bias,
    const float* __restrict__ Wr, const float* __restrict__ Wd,
    const float* __restrict__ bd, u16* __restrict__ xg,
    int* __restrict__ flags, float* __restrict__ out) {
  int* xgemm_done = flags;      // [8]
  int* scan_done = flags + 8;   // [8]
  const int tid = threadIdx.x;
  const int w = tid >> 6, lane = tid & 63;
  const int l16 = lane & 15, quad = lane >> 4;

  if (blockIdx.x >= 64) {
    // ================= xgemm worker (R8 tile internals) =================
    const int wid = blockIdx.x - 64;  // 0..191
    __shared__ u16 Al[64 * LDA];
    __shared__ float biasl[512];

    // B slice resident: cols 64w..64w+63, all K (loaded once)
    bf16x8 bfr[4][8];
#pragma unroll
    for (int nt = 0; nt < 4; ++nt) {
      const u16* bp = wkt + (64 * w + 16 * nt + l16) * 256 + quad * 8;
#pragma unroll
      for (int kt = 0; kt < 8; ++kt)
        bfr[nt][kt] = *(const bf16x8*)(bp + kt * 32);
    }
    biasl[tid] = bias[tid];
    const float gsc = ((w >> 1) == 2) ? 1.0f : -LOG2E;

    for (int c = 0; c < NCHUNK; ++c) {
      if (c >= 2) {
        if (tid == 0) spin_ge(&scan_done[c - 2], 64);  // half (c&1) free
        __syncthreads();
      }
      u16* xgc = xg + (c & 1) * XGHALF;
      for (int tau = wid; tau < 512; tau += 192) {
        const int gg = tau >> 5, tb = tau & 31;
        __syncthreads();  // protect Al from previous tile's readers
#pragma unroll
        for (int p = 0; p < 4; ++p) {
          int f = p * 512 + tid;
          int lr = f >> 5, ch = f & 31;
          int xi = (16 * gg + (lr & 15)) * 1024 + c * TC + tb * 4 + (lr >> 4);
          int idx = x[xi];
          *(uint4*)&Al[lr * LDA + ch * 8] = *(const uint4*)&embb[idx * 256 + ch * 8];
        }
        __syncthreads();

        f32x4 acc[4][4];
#pragma unroll
        for (int mt = 0; mt < 4; ++mt)
#pragma unroll
          for (int nt = 0; nt < 4; ++nt) acc[mt][nt] = f32x4{0.f, 0.f, 0.f, 0.f};
#pragma unroll
        for (int kt = 0; kt < 8; ++kt) {
          bf16x8 a[4];
#pragma unroll
          for (int mt = 0; mt < 4; ++mt)
            a[mt] = *(const bf16x8*)&Al[(mt * 16 + l16) * LDA + kt * 32 + quad * 8];
#pragma unroll
          for (int nt = 0; nt < 4; ++nt)
#pragma unroll
            for (int mt = 0; mt < 4; ++mt)
              acc[mt][nt] = __builtin_amdgcn_mfma_f32_16x16x32_bf16(
                  a[mt], bfr[nt][kt], acc[mt][nt], 0, 0, 0);
        }

        const size_t gtbase = ((size_t)(4 * gg + quad) * TC + tb * 4) * 2048;
#pragma unroll
        for (int nt = 0; nt < 4; ++nt) {
          float bv = biasl[64 * w + 16 * nt + l16];
          int tile = 4 * w + nt;
#pragma unroll
          for (int mt = 0; mt < 4; ++mt) {
            u64 pk = 0;
#pragma unroll
            for (int r = 0; r < 4; ++r)
              pk |= (u64)bf16bits((acc[mt][nt][r] + bv) * gsc) << (16 * r);
            size_t off = gtbase + (size_t)mt * 2048 + tile * 64 + l16 * 4;
            *(u64*)&xgc[off] = pk;
          }
        }
      }
      __syncthreads();  // drains vmcnt(0): all this wg's stores complete
      if (tid == 0) sig(&xgemm_done[c]);
    }
  } else {
    // ================= scan (R8 internals, persistent over 8 chunks) =====
    const int g = blockIdx.x;
    const int u = 16 * w + l16;
    __shared__ __align__(16) u16 hbuf[2][4 * 144];
    __shared__ __align__(16) u16 zrow[128];

    bf16x8 wf[4][4];
#pragma unroll
    for (int j = 0; j < 4; ++j) {
      const float sj = (j == 2) ? 1.0f : -LOG2E;
#pragma unroll
      for (int kt = 0; kt < 4; ++kt) {
        const float* p = Wr + (kt * 32 + quad * 8) * 512 + u + 128 * j;
#pragma unroll
        for (int jj = 0; jj < 8; ++jj) wf[j][kt][jj] = (bf16_t)(p[jj * 512] * sj);
      }
    }
    if (tid < 128) zrow[tid] = 0;
    float c1 = 0.f, h1 = 0.f;
    hbuf[0][quad * 144 + u] = bf16bits(0.f);

    const bool ald = (l16 & 3) == 0;
    const u16* rd0 = ald ? &hbuf[0][(l16 >> 2) * 144 + quad * 8] : &zrow[quad * 8];
    const u16* rd1 = ald ? &hbuf[1][(l16 >> 2) * 144 + quad * 8] : &zrow[quad * 8];
    u16* wr0 = &hbuf[0][quad * 144 + u];
    u16* wr1 = &hbuf[1][quad * 144 + u];

    for (int c = 0; c < NCHUNK; ++c) {
      if (tid == 0) spin_ge(&xgemm_done[c], 192);
      __syncthreads();  // also covers hbuf/zrow init on c==0

      const u16* xp = xg + (size_t)(c & 1) * XGHALF + (size_t)g * TC * 2048 +
                      w * 64 + l16 * 4 + quad;
      u16 xq0[4], xq1[4];
#pragma unroll
      for (int j = 0; j < 4; ++j) xq0[j] = xp[j * 512];
#pragma unroll
      for (int j = 0; j < 4; ++j) xq1[j] = xp[2048 + j * 512];
      xp += 2 * 2048;

      auto halfstep = [&](const u16* rd, u16* wr, u16* xv) {
        bf16x8 a[4];
#pragma unroll
        for (int kt = 0; kt < 4; ++kt)
          a[kt] = *(const bf16x8*)(rd + kt * 32);
        f32x4 acc[4];
#pragma unroll
        for (int j = 0; j < 4; ++j)
          acc[j] = f32x4{bf16f(xv[j]), 0.f, 0.f, 0.f};  // C-seed = xg
#pragma unroll
        for (int j = 0; j < 4; ++j)
#pragma unroll
          for (int kt = 0; kt < 4; ++kt)
            acc[j] = __builtin_amdgcn_mfma_f32_16x16x32_bf16(a[kt], wf[j][kt],
                                                             acc[j], 0, 0, 0);
        // re-prefetch 2 steps ahead (in flight across LDS_BARRIER; overshoot
        // at chunk edge lands in valid ws and is discarded)
#pragma unroll
        for (int j = 0; j < 4; ++j) xv[j] = xp[j * 512];
        xp += 2048;
        float ig = __builtin_amdgcn_rcpf(1.f + EXP2F(acc[0][0]));
        float fg = __builtin_amdgcn_rcpf(1.f + EXP2F(acc[1][0]));
        float og = __builtin_amdgcn_rcpf(1.f + EXP2F(acc[3][0]));
        float gg = fmaxf(acc[2][0], 0.f);
        c1 = fg * c1 + ig * gg;
        h1 = og * fmaxf(c1, 0.f);
        *wr = bf16bits(h1);
        LDS_BARRIER();
      };

      for (int t2 = 0; t2 < TC; t2 += 2) {
        halfstep(rd0, wr1, xq0);  // even t: read buf0, write buf1
        halfstep(rd1, wr0, xq1);  // odd t:  read buf1, write buf0
      }
      // all reads of half (c&1) consumed (in-flight overshoots are benign)
      if (tid == 0) sig(&scan_done[c]);
    }

    if (tid < 8) {  // final h in hbuf[0]
      int p = tid >> 1, jo = tid & 1;
      float o = bd[jo];
      for (int k = 0; k < 128; ++k)
        o += bf16f(hbuf[0][p * 144 + k]) * Wd[k * 2 + jo];
      out[(g * 4 + p) * 2 + jo] = o;
    }
  }
}

extern "C" void kernel_launch(void* const* d_in, const int* in_sizes, int n_in,
                              void* d_out, int out_size, void* d_ws, size_t ws_size,
                              hipStream_t stream) {
  const int* x = (const int*)d_in[0];
  const float* emb = (const float*)d_in[1];
  const float* Wk = (const float*)d_in[2];
  const float* Wr = (const float*)d_in[3];
  const float* bias = (const float*)d_in[4];
  const float* Wd = (const float*)d_in[5];
  const float* bd = (const float*)d_in[6];
  float* out = (float*)d_out;
  char* ws = (char*)d_ws;
  u16* xg = (u16*)(ws);
  u16* embb = (u16*)(ws + 67108864);
  u16* wkt = (u16*)(ws + 72228864);
  int* flags = (int*)(ws + 72491008);

  hipMemsetAsync(flags, 0, 16 * sizeof(int), stream);
  k_cvt_emb<<<10000, 256, 0, stream>>>(emb, embb, 2560000);
  k_wkt<<<512, 256, 0, stream>>>(Wk, wkt);
  k_pipe<<<256, 512, 0, stream>>>(x, embb, wkt, bias, Wr, Wd, bd, xg, flags, out);
}

// Round 12
// 629.156 us; speedup vs baseline: 1.8168x; 1.8168x over previous
//
#include <hip/hip_runtime.h>

typedef __bf16 bf16_t;
typedef __attribute__((ext_vector_type(8))) __bf16 bf16x8;
typedef __attribute__((ext_vector_type(4))) float f32x4;
typedef unsigned short u16;
typedef unsigned int u32;
typedef unsigned long long u64;

#define TC 128      // steps per chunk
#define NCH 8
#define XGHALF 16777216  // u16 elements per xg half (32 MB)
#define LDA 264   // 256 + 8 bf16 pad
#define LOG2E 1.44269504f

// LDS-visibility-only barrier: leaves global prefetch loads (vmcnt) in flight.
#define LDS_BARRIER() asm volatile("s_waitcnt lgkmcnt(0)\n\ts_barrier" ::: "memory")

#if __has_builtin(__builtin_amdgcn_exp2f)
#define EXP2F __builtin_amdgcn_exp2f
#else
static __device__ __forceinline__ float EXP2F(float x) {
  float r;
  asm volatile("v_exp_f32 %0, %1\n\ts_nop 1" : "=v"(r) : "v"(x));
  return r;
}
#endif

// ws layout (bytes), total ~72.8 MB (proven budget):
//   xg   @ 0         : 2 halves x 64*128*2048*2 = 67,108,864
//   embb @ 67108864  : 10000*256*2 = 5,120,000
//   wkt  @ 72228864  : 512*256*2   =   262,144
//   hst  @ 72491008  : 64*4*128*4  =   131,072  (f32 h carry [g][p][u])
//   cst  @ 72622080  : 64*4*128*4  =   131,072  (f32 c carry)
//
// xg half layout (u16): off = ((g*128 + t)*2048) + tile*64 + c16*4 + row4
//   g = b>>2, row4 = b&3, t = chunk-local step, tile = col>>4, c16 = col&15.
//   Scan lane (w,quad,l16) gate j reads (w+8j)*64 + l16*4 + quad.
//
// Overlap WITHOUT sync: launch cs runs scan(cs) on wgs 0-63 and xgemm(cs+1)
// on wgs 64-575 (one 64-row tile each) into the OTHER half. The half that
// scan(cs) reads was written entirely in launch cs-1 -> kernel-boundary
// visibility, no flags/atomics. Scan wgs have low blockIdx -> dispatch first.

static __device__ __forceinline__ u16 bf16bits(float v) {
  return __builtin_bit_cast(u16, (bf16_t)v);
}
static __device__ __forceinline__ float bf16f(u16 v) {
  return __builtin_bit_cast(float, (u32)v << 16);
}

__global__ __launch_bounds__(256) void k_cvt_emb(const float* __restrict__ e,
                                                 u16* __restrict__ o, int n) {
  int i = blockIdx.x * 256 + threadIdx.x;
  if (i < n) o[i] = bf16bits(e[i]);
}

// WkT[n][k] = Wk[k][n]  (Wk is [256][512] row-major)
__global__ __launch_bounds__(256) void k_wkt(const float* __restrict__ wk,
                                             u16* __restrict__ o) {
  int i = blockIdx.x * 256 + threadIdx.x;  // 131072 total
  int k = i & 255, n = i >> 8;
  o[i] = bf16bits(wk[k * 512 + n]);
}

__global__ __launch_bounds__(512) void k_fused(
    const int* __restrict__ x, const u16* __restrict__ embb,
    const u16* __restrict__ wkt, const float* __restrict__ bias,
    const float* __restrict__ Wr, const float* __restrict__ Wd,
    const float* __restrict__ bd, u16* __restrict__ xg,
    float* __restrict__ hstf, float* __restrict__ cstf,
    float* __restrict__ out, int cs) {
  const int tid = threadIdx.x;
  const int w = tid >> 6, lane = tid & 63;
  const int l16 = lane & 15, quad = lane >> 4;

  if (blockIdx.x >= 64) {
    // ============ xgemm worker: one 64-row tile of chunk cb = cs+1 ========
    const int cb = cs + 1;
    if (cb >= NCH) return;
    const int tau = blockIdx.x - 64;  // 0..511
    const int gg = tau >> 5, tb = tau & 31;
    u16* xgc = xg + (size_t)(cb & 1) * XGHALF;
    __shared__ u16 Al[64 * LDA];
    __shared__ float biasl[512];

    bf16x8 bfr[4][8];
#pragma unroll
    for (int nt = 0; nt < 4; ++nt) {
      const u16* bp = wkt + (64 * w + 16 * nt + l16) * 256 + quad * 8;
#pragma unroll
      for (int kt = 0; kt < 8; ++kt)
        bfr[nt][kt] = *(const bf16x8*)(bp + kt * 32);
    }

#pragma unroll
    for (int p = 0; p < 4; ++p) {
      int f = p * 512 + tid;
      int lr = f >> 5, ch = f & 31;
      int xi = (16 * gg + (lr & 15)) * 1024 + cb * TC + tb * 4 + (lr >> 4);
      int idx = x[xi];
      *(uint4*)&Al[lr * LDA + ch * 8] = *(const uint4*)&embb[idx * 256 + ch * 8];
    }
    biasl[tid] = bias[tid];
    __syncthreads();

    f32x4 acc[4][4];
#pragma unroll
    for (int mt = 0; mt < 4; ++mt)
#pragma unroll
      for (int nt = 0; nt < 4; ++nt) acc[mt][nt] = f32x4{0.f, 0.f, 0.f, 0.f};
#pragma unroll
    for (int kt = 0; kt < 8; ++kt) {
      bf16x8 a[4];
#pragma unroll
      for (int mt = 0; mt < 4; ++mt)
        a[mt] = *(const bf16x8*)&Al[(mt * 16 + l16) * LDA + kt * 32 + quad * 8];
#pragma unroll
      for (int nt = 0; nt < 4; ++nt)
#pragma unroll
        for (int mt = 0; mt < 4; ++mt)
          acc[mt][nt] = __builtin_amdgcn_mfma_f32_16x16x32_bf16(
              a[mt], bfr[nt][kt], acc[mt][nt], 0, 0, 0);
    }

    const float gsc = ((w >> 1) == 2) ? 1.0f : -LOG2E;
    const size_t gtbase = ((size_t)(4 * gg + quad) * TC + tb * 4) * 2048;
#pragma unroll
    for (int nt = 0; nt < 4; ++nt) {
      float bv = biasl[64 * w + 16 * nt + l16];
      int tile = 4 * w + nt;
#pragma unroll
      for (int mt = 0; mt < 4; ++mt) {
        u64 pk = 0;
#pragma unroll
        for (int r = 0; r < 4; ++r)
          pk |= (u64)bf16bits((acc[mt][nt][r] + bv) * gsc) << (16 * r);
        size_t off = gtbase + (size_t)mt * 2048 + tile * 64 + l16 * 4;
        *(u64*)&xgc[off] = pk;
      }
    }
  } else {
    // ================= scan chunk cs (R8 internals, TC=128) ==============
    if (cs < 0) return;
    const int g = blockIdx.x;
    const int u = 16 * w + l16;
    __shared__ __align__(16) u16 hbuf[2][4 * 144];
    __shared__ __align__(16) u16 zrow[128];

    bf16x8 wf[4][4];
#pragma unroll
    for (int j = 0; j < 4; ++j) {
      const float sj = (j == 2) ? 1.0f : -LOG2E;
#pragma unroll
      for (int kt = 0; kt < 4; ++kt) {
        const float* p = Wr + (kt * 32 + quad * 8) * 512 + u + 128 * j;
#pragma unroll
        for (int jj = 0; jj < 8; ++jj) wf[j][kt][jj] = (bf16_t)(p[jj * 512] * sj);
      }
    }
    if (tid < 128) zrow[tid] = 0;

    float c1 = 0.f, h1 = 0.f;
    if (cs != 0) {
      c1 = cstf[(g * 4 + quad) * 128 + u];
      h1 = hstf[(g * 4 + quad) * 128 + u];
    }
    hbuf[0][quad * 144 + u] = bf16bits(h1);

    const bool ald = (l16 & 3) == 0;
    const u16* rd0 = ald ? &hbuf[0][(l16 >> 2) * 144 + quad * 8] : &zrow[quad * 8];
    const u16* rd1 = ald ? &hbuf[1][(l16 >> 2) * 144 + quad * 8] : &zrow[quad * 8];
    u16* wr0 = &hbuf[0][quad * 144 + u];
    u16* wr1 = &hbuf[1][quad * 144 + u];

    const u16* xp = xg + (size_t)(cs & 1) * XGHALF + (size_t)g * TC * 2048 +
                    w * 64 + l16 * 4 + quad;
    u16 xq0[4], xq1[4];
#pragma unroll
    for (int j = 0; j < 4; ++j) xq0[j] = xp[j * 512];
#pragma unroll
    for (int j = 0; j < 4; ++j) xq1[j] = xp[2048 + j * 512];
    xp += 2 * 2048;

    __syncthreads();

    auto halfstep = [&](const u16* rd, u16* wr, u16* xv) {
      bf16x8 a[4];
#pragma unroll
      for (int kt = 0; kt < 4; ++kt)
        a[kt] = *(const bf16x8*)(rd + kt * 32);
      f32x4 acc[4];
#pragma unroll
      for (int j = 0; j < 4; ++j)
        acc[j] = f32x4{bf16f(xv[j]), 0.f, 0.f, 0.f};  // C-seed = xg
#pragma unroll
      for (int j = 0; j < 4; ++j)
#pragma unroll
        for (int kt = 0; kt < 4; ++kt)
          acc[j] = __builtin_amdgcn_mfma_f32_16x16x32_bf16(a[kt], wf[j][kt],
                                                           acc[j], 0, 0, 0);
      // re-prefetch 2 steps ahead (in flight across barrier; chunk-edge
      // overshoot lands in valid ws and is discarded)
#pragma unroll
      for (int j = 0; j < 4; ++j) xv[j] = xp[j * 512];
      xp += 2048;
      float ig = __builtin_amdgcn_rcpf(1.f + EXP2F(acc[0][0]));
      float fg = __builtin_amdgcn_rcpf(1.f + EXP2F(acc[1][0]));
      float og = __builtin_amdgcn_rcpf(1.f + EXP2F(acc[3][0]));
      float gg = fmaxf(acc[2][0], 0.f);
      c1 = fg * c1 + ig * gg;
      h1 = og * fmaxf(c1, 0.f);
      *wr = bf16bits(h1);
      LDS_BARRIER();
    };

    for (int t2 = 0; t2 < TC; t2 += 2) {
      halfstep(rd0, wr1, xq0);  // even t: read buf0, write buf1
      halfstep(rd1, wr0, xq1);  // odd t:  read buf1, write buf0
    }

    if (cs != NCH - 1) {
      cstf[(g * 4 + quad) * 128 + u] = c1;
      hstf[(g * 4 + quad) * 128 + u] = h1;
    } else if (tid < 8) {
      // final h in hbuf[0] (t=127 wrote buf 0; barrier passed)
      int p = tid >> 1, jo = tid & 1;
      float o = bd[jo];
      for (int k = 0; k < 128; ++k)
        o += bf16f(hbuf[0][p * 144 + k]) * Wd[k * 2 + jo];
      out[(g * 4 + p) * 2 + jo] = o;
    }
  }
}

extern "C" void kernel_launch(void* const* d_in, const int* in_sizes, int n_in,
                              void* d_out, int out_size, void* d_ws, size_t ws_size,
                              hipStream_t stream) {
  const int* x = (const int*)d_in[0];
  const float* emb = (const float*)d_in[1];
  const float* Wk = (const float*)d_in[2];
  const float* Wr = (const float*)d_in[3];
  const float* bias = (const float*)d_in[4];
  const float* Wd = (const float*)d_in[5];
  const float* bd = (const float*)d_in[6];
  float* out = (float*)d_out;
  char* ws = (char*)d_ws;
  u16* xg = (u16*)(ws);
  u16* embb = (u16*)(ws + 67108864);
  u16* wkt = (u16*)(ws + 72228864);
  float* hst = (float*)(ws + 72491008);
  float* cst = (float*)(ws + 72622080);

  k_cvt_emb<<<10000, 256, 0, stream>>>(emb, embb, 2560000);
  k_wkt<<<512, 256, 0, stream>>>(Wk, wkt);
  // cs=-1: xgemm(0) only; cs=0..6: scan(cs) || xgemm(cs+1); cs=7: scan(7)
  for (int cs = -1; cs < NCH; ++cs) {
    int nwg = (cs + 1 < NCH) ? 576 : 64;
    k_fused<<<nwg, 512, 0, stream>>>(x, embb, wkt, bias, Wr, Wd, bd, xg,
                                     hst, cst, out, cs);
  }
}

// Round 13
// 603.501 us; speedup vs baseline: 1.8940x; 1.0425x over previous
//
#include <hip/hip_runtime.h>

typedef __bf16 bf16_t;
typedef __attribute__((ext_vector_type(8))) __bf16 bf16x8;
typedef __attribute__((ext_vector_type(4))) float f32x4;
typedef unsigned short u16;
typedef unsigned int u32;
typedef unsigned long long u64;

#define TC 128      // steps per chunk
#define NCH 8
#define XGHALF 16777216  // u16 elements per xg half (33.5 MB)
#define LDA 264   // 256 + 8 bf16 pad
#define LOG2E 1.44269504f

// LDS-visibility-only barrier: leaves global prefetch loads (vmcnt) in flight.
#define LDS_BARRIER() asm volatile("s_waitcnt lgkmcnt(0)\n\ts_barrier" ::: "memory")

#if __has_builtin(__builtin_amdgcn_exp2f)
#define EXP2F __builtin_amdgcn_exp2f
#else
static __device__ __forceinline__ float EXP2F(float x) {
  float r;
  asm volatile("v_exp_f32 %0, %1\n\ts_nop 1" : "=v"(r) : "v"(x));
  return r;
}
#endif

// ws layout (bytes), total ~72.9 MB (R9-proven budget):
//   xg   @ 0         : 2 halves x 64*128*2048*2 = 67,108,864
//   embb @ 67108864  : 10000*256*2 = 5,120,000
//   wkt  @ 72228864  : 512*256*2   =   262,144
//   hst  @ 72491008  : 64*4*128*4  =   131,072  (f32 h carry [g][p][u])
//   cst  @ 72622080  : 64*4*128*4  =   131,072  (f32 c carry)
//   wrt  @ 72753152  : 512*128*2   =   131,072  (bf16 Wr frags, scan layout)
//
// xg half layout (u16): off = ((g*128 + t)*2048) + tile*64 + c16*4 + row4
//   Scan lane (w,quad,l16) gate j reads (w+8j)*64 + l16*4 + quad.
//
// Launch cs: wgs 0-63 scan chunk cs (half cs&1); wgs 64-575 xgemm chunk cs+1
// into the other half (producer ran in the PREVIOUS launch -> kernel-boundary
// visibility, no flags). cs=-1 additionally carries bake wgs (wkt/wrt/embb)
// while its xgemm workers read raw f32 emb/Wk (bitwise-identical bf16 casts).

static __device__ __forceinline__ u16 bf16bits(float v) {
  return __builtin_bit_cast(u16, (bf16_t)v);
}
static __device__ __forceinline__ float bf16f(u16 v) {
  return __builtin_bit_cast(float, (u32)v << 16);
}

__global__ __launch_bounds__(512) void k_fused(
    const int* __restrict__ x, const float* __restrict__ emb,
    u16* __restrict__ embb, const float* __restrict__ Wk,
    u16* __restrict__ wkt, const float* __restrict__ Wr,
    u16* __restrict__ wrt, const float* __restrict__ bias,
    const float* __restrict__ Wd, const float* __restrict__ bd,
    u16* __restrict__ xg, float* __restrict__ hstf, float* __restrict__ cstf,
    float* __restrict__ out, int cs) {
  const int tid = threadIdx.x;
  const int w = tid >> 6, lane = tid & 63;
  const int l16 = lane & 15, quad = lane >> 4;

  if (blockIdx.x >= 585) {
    // ---- embb bake (cs==-1 only): bf16 embedding table for later launches
    for (int i = (blockIdx.x - 585) * 512 + tid; i < 2560000; i += 262144)
      embb[i] = bf16bits(emb[i]);
    return;
  }
  if (blockIdx.x == 584) {
    // ---- wrt bake (cs==-1 only): Wr frags in scan thread layout, gate-scaled
    const int u = 16 * w + l16;
#pragma unroll
    for (int j = 0; j < 4; ++j) {
      const float sj = (j == 2) ? 1.0f : -LOG2E;
#pragma unroll
      for (int kt = 0; kt < 4; ++kt)
#pragma unroll
        for (int jj = 0; jj < 8; ++jj)
          wrt[tid * 128 + (j * 4 + kt) * 8 + jj] =
              bf16bits(Wr[(kt * 32 + quad * 8 + jj) * 512 + u + 128 * j] * sj);
    }
    return;
  }
  if (blockIdx.x >= 576) {
    // ---- wkt bake (cs==-1 only): WkT[n][k] = Wk[k][n]
    for (int i = (blockIdx.x - 576) * 512 + tid; i < 131072; i += 4096) {
      int k = i & 255, n = i >> 8;
      wkt[i] = bf16bits(Wk[k * 512 + n]);
    }
    return;
  }

  if (blockIdx.x >= 64) {
    // ============ xgemm worker: one 64-row tile of chunk cb = cs+1 ========
    const int cb = cs + 1;
    if (cb >= NCH) return;
    const bool raw = (cs < 0);  // first launch: read f32 emb/Wk directly
    const int tau = blockIdx.x - 64;  // 0..511
    const int gg = tau >> 5, tb = tau & 31;
    u16* xgc = xg + (size_t)(cb & 1) * XGHALF;
    __shared__ u16 Al[64 * LDA];
    __shared__ float biasl[512];

    bf16x8 bfr[4][8];
    if (raw) {
#pragma unroll
      for (int nt = 0; nt < 4; ++nt)
#pragma unroll
        for (int kt = 0; kt < 8; ++kt)
#pragma unroll
          for (int jj = 0; jj < 8; ++jj)
            bfr[nt][kt][jj] =
                (bf16_t)Wk[(kt * 32 + quad * 8 + jj) * 512 + 64 * w + 16 * nt + l16];
    } else {
#pragma unroll
      for (int nt = 0; nt < 4; ++nt) {
        const u16* bp = wkt + (64 * w + 16 * nt + l16) * 256 + quad * 8;
#pragma unroll
        for (int kt = 0; kt < 8; ++kt)
          bfr[nt][kt] = *(const bf16x8*)(bp + kt * 32);
      }
    }

#pragma unroll
    for (int p = 0; p < 4; ++p) {
      int f = p * 512 + tid;
      int lr = f >> 5, ch = f & 31;
      int xi = (16 * gg + (lr & 15)) * 1024 + cb * TC + tb * 4 + (lr >> 4);
      int idx = x[xi];
      if (raw) {
        const float* ep = emb + idx * 256 + ch * 8;
        u16 tmp[8];
#pragma unroll
        for (int e = 0; e < 8; ++e) tmp[e] = bf16bits(ep[e]);
        *(uint4*)&Al[lr * LDA + ch * 8] = *(const uint4*)tmp;
      } else {
        *(uint4*)&Al[lr * LDA + ch * 8] = *(const uint4*)&embb[idx * 256 + ch * 8];
      }
    }
    biasl[tid] = bias[tid];
    __syncthreads();

    f32x4 acc[4][4];
#pragma unroll
    for (int mt = 0; mt < 4; ++mt)
#pragma unroll
      for (int nt = 0; nt < 4; ++nt) acc[mt][nt] = f32x4{0.f, 0.f, 0.f, 0.f};
#pragma unroll
    for (int kt = 0; kt < 8; ++kt) {
      bf16x8 a[4];
#pragma unroll
      for (int mt = 0; mt < 4; ++mt)
        a[mt] = *(const bf16x8*)&Al[(mt * 16 + l16) * LDA + kt * 32 + quad * 8];
#pragma unroll
      for (int nt = 0; nt < 4; ++nt)
#pragma unroll
        for (int mt = 0; mt < 4; ++mt)
          acc[mt][nt] = __builtin_amdgcn_mfma_f32_16x16x32_bf16(
              a[mt], bfr[nt][kt], acc[mt][nt], 0, 0, 0);
    }

    const float gsc = ((w >> 1) == 2) ? 1.0f : -LOG2E;
    const size_t gtbase = ((size_t)(4 * gg + quad) * TC + tb * 4) * 2048;
#pragma unroll
    for (int nt = 0; nt < 4; ++nt) {
      float bv = biasl[64 * w + 16 * nt + l16];
      int tile = 4 * w + nt;
#pragma unroll
      for (int mt = 0; mt < 4; ++mt) {
        u64 pk = 0;
#pragma unroll
        for (int r = 0; r < 4; ++r)
          pk |= (u64)bf16bits((acc[mt][nt][r] + bv) * gsc) << (16 * r);
        size_t off = gtbase + (size_t)mt * 2048 + tile * 64 + l16 * 4;
        *(u64*)&xgc[off] = pk;
      }
    }
  } else {
    // ================= scan chunk cs (R8 internals, TC=128) ==============
    if (cs < 0) return;
    const int g = blockIdx.x;
    const int u = 16 * w + l16;
    __shared__ __align__(16) u16 hbuf[2][4 * 144];
    __shared__ __align__(16) u16 zrow[128];

    // wf preload from pre-baked wrt: 16 coalesced b128 loads
    bf16x8 wf[4][4];
    {
      const u16* wp = wrt + tid * 128;
#pragma unroll
      for (int j = 0; j < 4; ++j)
#pragma unroll
        for (int kt = 0; kt < 4; ++kt)
          wf[j][kt] = *(const bf16x8*)(wp + (j * 4 + kt) * 8);
    }
    if (tid < 128) zrow[tid] = 0;

    float c1 = 0.f, h1 = 0.f;
    if (cs != 0) {
      c1 = cstf[(g * 4 + quad) * 128 + u];
      h1 = hstf[(g * 4 + quad) * 128 + u];
    }
    hbuf[0][quad * 144 + u] = bf16bits(h1);

    const bool ald = (l16 & 3) == 0;
    const u16* rd0 = ald ? &hbuf[0][(l16 >> 2) * 144 + quad * 8] : &zrow[quad * 8];
    const u16* rd1 = ald ? &hbuf[1][(l16 >> 2) * 144 + quad * 8] : &zrow[quad * 8];
    u16* wr0 = &hbuf[0][quad * 144 + u];
    u16* wr1 = &hbuf[1][quad * 144 + u];

    const u16* xp = xg + (size_t)(cs & 1) * XGHALF + (size_t)g * TC * 2048 +
                    w * 64 + l16 * 4 + quad;
    u16 xq0[4], xq1[4];
#pragma unroll
    for (int j = 0; j < 4; ++j) xq0[j] = xp[j * 512];
#pragma unroll
    for (int j = 0; j < 4; ++j) xq1[j] = xp[2048 + j * 512];
    xp += 2 * 2048;

    __syncthreads();

    auto halfstep = [&](const u16* rd, u16* wr, u16* xv) {
      bf16x8 a[4];
#pragma unroll
      for (int kt = 0; kt < 4; ++kt)
        a[kt] = *(const bf16x8*)(rd + kt * 32);
      f32x4 acc[4];
#pragma unroll
      for (int j = 0; j < 4; ++j)
        acc[j] = f32x4{bf16f(xv[j]), 0.f, 0.f, 0.f};  // C-seed = xg
#pragma unroll
      for (int j = 0; j < 4; ++j)
#pragma unroll
        for (int kt = 0; kt < 4; ++kt)
          acc[j] = __builtin_amdgcn_mfma_f32_16x16x32_bf16(a[kt], wf[j][kt],
                                                           acc[j], 0, 0, 0);
      // re-prefetch 2 steps ahead (in flight across barrier; chunk-edge
      // overshoot lands in valid ws and is discarded)
#pragma unroll
      for (int j = 0; j < 4; ++j) xv[j] = xp[j * 512];
      xp += 2048;
      float ig = __builtin_amdgcn_rcpf(1.f + EXP2F(acc[0][0]));
      float fg = __builtin_amdgcn_rcpf(1.f + EXP2F(acc[1][0]));
      float og = __builtin_amdgcn_rcpf(1.f + EXP2F(acc[3][0]));
      float gg = fmaxf(acc[2][0], 0.f);
      c1 = fg * c1 + ig * gg;
      h1 = og * fmaxf(c1, 0.f);
      *wr = bf16bits(h1);
      LDS_BARRIER();
    };

    for (int t2 = 0; t2 < TC; t2 += 2) {
      halfstep(rd0, wr1, xq0);  // even t: read buf0, write buf1
      halfstep(rd1, wr0, xq1);  // odd t:  read buf1, write buf0
    }

    if (cs != NCH - 1) {
      cstf[(g * 4 + quad) * 128 + u] = c1;
      hstf[(g * 4 + quad) * 128 + u] = h1;
    } else if (tid < 8) {
      // final h in hbuf[0] (t=127 wrote buf 0; barrier passed)
      int p = tid >> 1, jo = tid & 1;
      float o = bd[jo];
      for (int k = 0; k < 128; ++k)
        o += bf16f(hbuf[0][p * 144 + k]) * Wd[k * 2 + jo];
      out[(g * 4 + p) * 2 + jo] = o;
    }
  }
}

extern "C" void kernel_launch(void* const* d_in, const int* in_sizes, int n_in,
                              void* d_out, int out_size, void* d_ws, size_t ws_size,
                              hipStream_t stream) {
  const int* x = (const int*)d_in[0];
  const float* emb = (const float*)d_in[1];
  const float* Wk = (const float*)d_in[2];
  const float* Wr = (const float*)d_in[3];
  const float* bias = (const float*)d_in[4];
  const float* Wd = (const float*)d_in[5];
  const float* bd = (const float*)d_in[6];
  float* out = (float*)d_out;
  char* ws = (char*)d_ws;
  u16* xg = (u16*)(ws);
  u16* embb = (u16*)(ws + 67108864);
  u16* wkt = (u16*)(ws + 72228864);
  float* hst = (float*)(ws + 72491008);
  float* cst = (float*)(ws + 72622080);
  u16* wrt = (u16*)(ws + 72753152);

  // cs=-1: xgemm(0) from raw f32 + bake embb/wkt/wrt; cs=0..6: scan(cs) ||
  // xgemm(cs+1); cs=7: scan(7) only. No prelude kernels, no sync primitives.
  for (int cs = -1; cs < NCH; ++cs) {
    int nwg = (cs < 0) ? 1097 : ((cs + 1 < NCH) ? 576 : 64);
    k_fused<<<nwg, 512, 0, stream>>>(x, emb, embb, Wk, wkt, Wr, wrt, bias,
                                     Wd, bd, xg, hst, cst, out, cs);
  }
}